// Round 17
// baseline (160.766 us; speedup 1.0000x reference)
//
#include <hip/hip_runtime.h>
#include <hip/hip_bf16.h>
#include <math.h>

#define B_ 32
#define T_ 128
#define C_ 64
#define E_ 8
#define HID_ 32

#define LOG2E 1.44269504088896341f

__device__ __forceinline__ float fast_rcp(float x) { return __builtin_amdgcn_rcpf(x); }
__device__ __forceinline__ float fast_exp2(float x) { return exp2f(x); }
__device__ __forceinline__ float fast_sigmoid(float x) {
    return fast_rcp(1.0f + fast_exp2(-LOG2E * x));
}
__device__ __forceinline__ float fast_tanh(float x) {
    float xc = __builtin_amdgcn_fmed3f(x, -15.0f, 15.0f);
    float t = fast_exp2(2.0f * LOG2E * xc);
    return (t - 1.0f) * fast_rcp(t + 1.0f);
}

// quad_perm DPP: lane i reads lane perm(i) within its quad. VALU pipe (~8cyc),
// vs ds_bpermute's ~120cyc LDS-pipe latency.
template <int CTRL>
__device__ __forceinline__ float qperm(float v) {
    return __int_as_float(__builtin_amdgcn_update_dpp(
        __float_as_int(v), __float_as_int(v), CTRL, 0xF, 0xF, false));
}
#define ROT1 0x39   // {1,2,3,0}
#define ROT2 0x4E   // {2,3,0,1}
#define ROT3 0x93   // {3,0,1,2}

// ---------------------------------------------------------------------------
// K0: xp row + ts_imp for one (b,t). grid = B*T, block = 64.
// ---------------------------------------------------------------------------
__global__ __launch_bounds__(64) void k_pre_ts(
    const float* __restrict__ x, const float* __restrict__ W_in, const float* __restrict__ b_in,
    const float* __restrict__ W_ts1, const float* __restrict__ b_ts1,
    const float* __restrict__ W_ts2, const float* __restrict__ b_ts2,
    float* __restrict__ xp, float* __restrict__ ts_imp)
{
    const int bt = blockIdx.x;
    const int tid = threadIdx.x;
    __shared__ __align__(16) float xs[C_];
    __shared__ float h1[16];
    if (tid < 16) ((float4*)xs)[tid] = ((const float4*)(x + bt * C_))[tid];
    __syncthreads();

    // xp[bt][tid] = b_in[tid] + x . W_in[tid,:]
    float a = b_in[tid];
    const float4* w4 = (const float4*)(W_in + tid * C_);
#pragma unroll
    for (int k4 = 0; k4 < 16; ++k4) {
        float4 xv = ((const float4*)xs)[k4];
        float4 wv = w4[k4];
        a = fmaf(xv.x, wv.x, a); a = fmaf(xv.y, wv.y, a);
        a = fmaf(xv.z, wv.z, a); a = fmaf(xv.w, wv.w, a);
    }
    xp[bt * C_ + tid] = a;

    if (tid < 16) {
        float s = b_ts1[tid];
#pragma unroll
        for (int k = 0; k < C_; ++k) s = fmaf(xs[k], W_ts1[tid * C_ + k], s);
        h1[tid] = 0.5f * s * (1.0f + erff(s * 0.70710678118654752f));
    }
    __syncthreads();
    if (tid == 0) {
        float s = b_ts2[0];
#pragma unroll
        for (int k = 0; k < 16; ++k) s = fmaf(h1[k], W_ts2[k], s);
        ts_imp[bt] = fast_sigmoid(s);
    }
}

// ---------------------------------------------------------------------------
// K1: GRU, 4 lanes/chain (2 units each), h-exchange via quad_perm DPP.
// 16 chains per 64-thread block, grid = 128. Weights load-time permuted to
// rotation order: pair m of lane q = units {2((q+m)&3), 2((q+m)&3)+1}.
// ---------------------------------------------------------------------------
__global__ __launch_bounds__(64) void k_gru(
    const float* __restrict__ xp, const float* __restrict__ W_ih, const float* __restrict__ W_hh,
    const float* __restrict__ b_ih, const float* __restrict__ b_hh,
    float* __restrict__ hs, float* __restrict__ fh)
{
    const int tid = threadIdx.x;
    const int ci = tid >> 2;                    // chain-in-block 0..15
    const int q  = tid & 3;                     // lane-in-quad
    const int chain = blockIdx.x * 16 + ci;
    const int c = chain & 63;

    __shared__ float xc[16][T_ + 1];

    const int c_base = (blockIdx.x & 3) * 16;
    const int bb = blockIdx.x >> 2;
    for (int idx = tid; idx < 16 * T_; idx += 64) {
        int cci = idx & 15;
        int t = idx >> 4;
        xc[cci][t] = xp[(bb * T_ + t) * C_ + c_base + cci];
    }
    __syncthreads();

    float wr[2][8], wz[2][8], wn[2][8];
    float wir[2], wiz[2], win_[2], cr[2], cz[2], bin_[2], bhn[2];
#pragma unroll
    for (int u = 0; u < 2; ++u) {
        const int e = 2 * q + u;
#pragma unroll
        for (int m = 0; m < 4; ++m) {
#pragma unroll
            for (int p = 0; p < 2; ++p) {
                const int j = 2 * ((q + m) & 3) + p;
                wr[u][2 * m + p] = W_hh[(c * 24 + 0  + e) * 8 + j];
                wz[u][2 * m + p] = W_hh[(c * 24 + 8  + e) * 8 + j];
                wn[u][2 * m + p] = W_hh[(c * 24 + 16 + e) * 8 + j];
            }
        }
        wir[u] = W_ih[c * 24 + e];
        wiz[u] = W_ih[c * 24 + 8 + e];
        win_[u] = W_ih[c * 24 + 16 + e];
        cr[u] = b_ih[c * 24 + e] + b_hh[c * 24 + e];
        cz[u] = b_ih[c * 24 + 8 + e] + b_hh[c * 24 + 8 + e];
        bin_[u] = b_ih[c * 24 + 16 + e];
        bhn[u]  = b_hh[c * 24 + 16 + e];
    }

    float ha = 0.0f, hb = 0.0f;                 // h[2q], h[2q+1]
    float* hop = hs + (size_t)chain * T_ * E_ + 2 * q;
    float xv = xc[ci][0];
    for (int t = 0; t < T_; ++t) {
        float xvn = xc[ci][t + 1];              // pad makes t=127 safe
        // quad all-gather via independent DPP rotations (VALU pipe)
        float pa1 = qperm<ROT1>(ha), pb1 = qperm<ROT1>(hb);
        float pa2 = qperm<ROT2>(ha), pb2 = qperm<ROT2>(hb);
        float pa3 = qperm<ROT3>(ha), pb3 = qperm<ROT3>(hb);
        const float pa[4] = {ha, pa1, pa2, pa3};
        const float pb[4] = {hb, pb1, pb2, pb3};
        float hnew[2];
#pragma unroll
        for (int u = 0; u < 2; ++u) {
            float g0 = fmaf(pb[0], wr[u][1], pa[0] * wr[u][0]);
            float g1 = fmaf(pb[1], wr[u][3], pa[1] * wr[u][2]);
            float g2 = fmaf(pb[2], wr[u][5], pa[2] * wr[u][4]);
            float g3 = fmaf(pb[3], wr[u][7], pa[3] * wr[u][6]);
            float gr = fmaf(xv, wir[u], cr[u]) + ((g0 + g1) + (g2 + g3));
            float z0 = fmaf(pb[0], wz[u][1], pa[0] * wz[u][0]);
            float z1 = fmaf(pb[1], wz[u][3], pa[1] * wz[u][2]);
            float z2 = fmaf(pb[2], wz[u][5], pa[2] * wz[u][4]);
            float z3 = fmaf(pb[3], wz[u][7], pa[3] * wz[u][6]);
            float gz = fmaf(xv, wiz[u], cz[u]) + ((z0 + z1) + (z2 + z3));
            float n0 = fmaf(pb[0], wn[u][1], pa[0] * wn[u][0]);
            float n1 = fmaf(pb[1], wn[u][3], pa[1] * wn[u][2]);
            float n2 = fmaf(pb[2], wn[u][5], pa[2] * wn[u][4]);
            float n3 = fmaf(pb[3], wn[u][7], pa[3] * wn[u][6]);
            float hn = bhn[u] + ((n0 + n1) + (n2 + n3));
            float gn = fmaf(xv, win_[u], bin_[u]);
            float r = fast_sigmoid(gr);
            float z = fast_sigmoid(gz);
            float nn = fast_tanh(fmaf(r, hn, gn));
            float hu = (u == 0) ? ha : hb;
            hnew[u] = fmaf(z, hu - nn, nn);
        }
        ha = hnew[0]; hb = hnew[1];
        *(float2*)(hop + (size_t)t * E_) = make_float2(ha, hb);
        xv = xvn;
    }
    fh[chain * E_ + 2 * q] = ha;
    fh[chain * E_ + 2 * q + 1] = hb;
}

// ---------------------------------------------------------------------------
// K2 (fat): blocks 0..2047 = attention per (b,c) [r14 proven structure,
// barrier-light epilogue]; block 2048 = out0.
// ---------------------------------------------------------------------------
__global__ __launch_bounds__(256) void k_attn_out(
    const float* __restrict__ hs, const float* __restrict__ W_qkv, const float* __restrict__ b_qkv,
    const float* __restrict__ W_o, const float* __restrict__ b_o,
    const float* __restrict__ fh, const float* __restrict__ W_out, const float* __restrict__ b_out,
    float* __restrict__ out0, float* __restrict__ feat_imp, float* __restrict__ tsf_imp)
{
    const int tid = threadIdx.x;

    if (blockIdx.x == B_ * C_) {
#pragma unroll
        for (int pi = tid; pi < B_ * HID_; pi += 256) {
            int bb = pi >> 5, o = pi & 31;
            const float4* hv = (const float4*)(fh + bb * C_ * E_);
            const float4* wv = (const float4*)(W_out + o * C_ * E_);
            float a = b_out[o];
#pragma unroll 16
            for (int k4 = 0; k4 < 128; ++k4) {
                float4 h4 = hv[k4], w4 = wv[k4];
                a = fmaf(h4.x, w4.x, a); a = fmaf(h4.y, w4.y, a);
                a = fmaf(h4.z, w4.z, a); a = fmaf(h4.w, w4.w, a);
            }
            out0[pi] = a;
        }
        return;
    }

    const int bc = blockIdx.x;
    const int b = bc >> 6, c = bc & 63;
    const int t2 = tid & 63;
    const int sq = tid >> 6;

    __shared__ __align__(16) float ks[T_][E_];
    __shared__ __align__(16) float us[T_][4];
    __shared__ float qsT[E_][T_];
    __shared__ float pacc[3][T_][8];

    const float qscale = 0.70710678118654752f * LOG2E;

    // staging: tid<128 -> q+k of row tid; tid>=128 -> u of row tid-128
    {
        const int row = (tid < 128) ? tid : (tid - 128);
        const float4* hp = (const float4*)(hs + (size_t)bc * T_ * E_ + row * E_);
        float4 h0 = hp[0], h1 = hp[1];
        float hr[E_] = {h0.x, h0.y, h0.z, h0.w, h1.x, h1.y, h1.z, h1.w};
        if (tid < 128) {
            float kv[E_];
#pragma unroll
            for (int f = 0; f < E_; ++f) {
                float a = b_qkv[E_ + f];
#pragma unroll
                for (int j = 0; j < E_; ++j) a = fmaf(hr[j], W_qkv[(E_ + f) * E_ + j], a);
                kv[f] = a;
            }
            ((float4*)&ks[row][0])[0] = make_float4(kv[0], kv[1], kv[2], kv[3]);
            ((float4*)&ks[row][0])[1] = make_float4(kv[4], kv[5], kv[6], kv[7]);
#pragma unroll
            for (int f = 0; f < E_; ++f) {
                float a = b_qkv[f];
#pragma unroll
                for (int j = 0; j < E_; ++j) a = fmaf(hr[j], W_qkv[f * E_ + j], a);
                qsT[f][row] = a * qscale;
            }
        } else {
            float ws[E_];
#pragma unroll
            for (int d = 0; d < E_; ++d) {
                float wv = 0.0f;
#pragma unroll
                for (int fp = 0; fp < E_; ++fp) wv += W_o[fp * E_ + d];
                ws[d] = wv;
            }
            float vv[E_];
#pragma unroll
            for (int f = 0; f < E_; ++f) {
                float a = b_qkv[2 * E_ + f];
#pragma unroll
                for (int j = 0; j < E_; ++j) a = fmaf(hr[j], W_qkv[(2 * E_ + f) * E_ + j], a);
                vv[f] = a;
            }
            float4 uu;
            uu.x = fmaf(vv[1], ws[1], vv[0] * ws[0]);
            uu.y = fmaf(vv[3], ws[3], vv[2] * ws[2]);
            uu.z = fmaf(vv[5], ws[5], vv[4] * ws[4]);
            uu.w = fmaf(vv[7], ws[7], vv[6] * ws[6]);
            *((float4*)&us[row][0]) = uu;
        }
    }
    __syncthreads();

    float q0[E_], q1[E_];
#pragma unroll
    for (int f = 0; f < E_; ++f) { q0[f] = qsT[f][t2]; q1[f] = qsT[f][t2 + 64]; }

    float l0[4] = {0.f,0.f,0.f,0.f}, S0[4] = {0.f,0.f,0.f,0.f};
    float l1[4] = {0.f,0.f,0.f,0.f}, S1[4] = {0.f,0.f,0.f,0.f};
    const float* kb = &ks[sq * 32][0];
    const float* ub = &us[sq * 32][0];
#pragma unroll 8
    for (int i = 0; i < 32; ++i) {
        float4 k0 = *(const float4*)(kb + i * 8);
        float4 k1 = *(const float4*)(kb + i * 8 + 4);
        float4 uu = *(const float4*)(ub + i * 4);
        float p00 = fast_exp2(fmaf(q0[1], k0.y, q0[0] * k0.x));
        float p01 = fast_exp2(fmaf(q0[3], k0.w, q0[2] * k0.z));
        float p02 = fast_exp2(fmaf(q0[5], k1.y, q0[4] * k1.x));
        float p03 = fast_exp2(fmaf(q0[7], k1.w, q0[6] * k1.z));
        float p10 = fast_exp2(fmaf(q1[1], k0.y, q1[0] * k0.x));
        float p11 = fast_exp2(fmaf(q1[3], k0.w, q1[2] * k0.z));
        float p12 = fast_exp2(fmaf(q1[5], k1.y, q1[4] * k1.x));
        float p13 = fast_exp2(fmaf(q1[7], k1.w, q1[6] * k1.z));
        l0[0] += p00; l0[1] += p01; l0[2] += p02; l0[3] += p03;
        l1[0] += p10; l1[1] += p11; l1[2] += p12; l1[3] += p13;
        S0[0] = fmaf(p00, uu.x, S0[0]); S0[1] = fmaf(p01, uu.y, S0[1]);
        S0[2] = fmaf(p02, uu.z, S0[2]); S0[3] = fmaf(p03, uu.w, S0[3]);
        S1[0] = fmaf(p10, uu.x, S1[0]); S1[1] = fmaf(p11, uu.y, S1[1]);
        S1[2] = fmaf(p12, uu.z, S1[2]); S1[3] = fmaf(p13, uu.w, S1[3]);
    }

    if (sq > 0) {
        float* pr = &pacc[sq - 1][t2][0];
#pragma unroll
        for (int i = 0; i < 4; ++i) { pr[i] = l0[i]; pr[4 + i] = S0[i]; }
        pr = &pacc[sq - 1][t2 + 64][0];
#pragma unroll
        for (int i = 0; i < 4; ++i) { pr[i] = l1[i]; pr[4 + i] = S1[i]; }
    }
    __syncthreads();

    if (sq == 0) {
        float bsum = 0.0f;
#pragma unroll
        for (int fp = 0; fp < E_; ++fp) bsum += b_o[fp];
#pragma unroll
        for (int qq = 0; qq < 3; ++qq) {
#pragma unroll
            for (int i = 0; i < 4; ++i) {
                l0[i] += pacc[qq][t2][i];       S0[i] += pacc[qq][t2][4 + i];
                l1[i] += pacc[qq][t2 + 64][i];  S1[i] += pacc[qq][t2 + 64][4 + i];
            }
        }
        float Sa = bsum, Sb = bsum;
#pragma unroll
        for (int hh = 0; hh < 4; ++hh) {
            Sa = fmaf(S0[hh], fast_rcp(l0[hh]), Sa);
            Sb = fmaf(S1[hh], fast_rcp(l1[hh]), Sb);
        }
        tsf_imp[(size_t)b * T_ * C_ + (size_t)t2 * C_ + c] = fast_sigmoid(Sa);
        tsf_imp[(size_t)b * T_ * C_ + (size_t)(t2 + 64) * C_ + c] = fast_sigmoid(Sb);
        // wave-local butterfly: sums all 128 rows (2 per lane), no barriers
        float fsum = Sa + Sb;
#pragma unroll
        for (int off = 1; off <= 32; off <<= 1) fsum += __shfl_xor(fsum, off);
        if (t2 == 0) feat_imp[bc] = fast_sigmoid(fsum);
    }
}

// ---------------------------------------------------------------------------
extern "C" void kernel_launch(void* const* d_in, const int* in_sizes, int n_in,
                              void* d_out, int out_size, void* d_ws, size_t ws_size,
                              hipStream_t stream) {
    (void)in_sizes; (void)n_in; (void)out_size; (void)ws_size;

    float* out0 = (float*)d_out;                 // (B, HID)    1024
    float* feat = out0 + B_ * HID_;              // (B, C)      2048
    float* tsim = feat + B_ * C_;                // (B, T)      4096
    float* tsf  = tsim + B_ * T_;                // (B, T, C) 262144

    const float* x     = (const float*)d_in[0];
    const float* W_in  = (const float*)d_in[1];
    const float* b_in  = (const float*)d_in[2];
    const float* W_ts1 = (const float*)d_in[3];
    const float* b_ts1 = (const float*)d_in[4];
    const float* W_ts2 = (const float*)d_in[5];
    const float* b_ts2 = (const float*)d_in[6];
    const float* W_ih  = (const float*)d_in[7];
    const float* W_hh  = (const float*)d_in[8];
    const float* b_ih  = (const float*)d_in[9];
    const float* b_hh  = (const float*)d_in[10];
    const float* W_qkv = (const float*)d_in[11];
    const float* b_qkv = (const float*)d_in[12];
    const float* W_o   = (const float*)d_in[13];
    const float* b_o   = (const float*)d_in[14];
    const float* W_out = (const float*)d_in[15];
    const float* b_out = (const float*)d_in[16];

    // ws layout (f32): fh (64KB) | xp (1MB) | hs (8MB)
    float* fhb = (float*)d_ws;
    float* xpb = fhb + B_ * C_ * E_;
    float* hsb = xpb + (size_t)B_ * T_ * C_;

    hipLaunchKernelGGL(k_pre_ts, dim3(B_ * T_), dim3(64), 0, stream,
                       x, W_in, b_in, W_ts1, b_ts1, W_ts2, b_ts2, xpb, tsim);
    hipLaunchKernelGGL(k_gru, dim3(B_ * C_ / 16), dim3(64), 0, stream,
                       xpb, W_ih, W_hh, b_ih, b_hh, hsb, fhb);
    hipLaunchKernelGGL(k_attn_out, dim3(B_ * C_ + 1), dim3(256), 0, stream,
                       hsb, W_qkv, b_qkv, W_o, b_o,
                       fhb, W_out, b_out, out0, feat, tsf);
}

// Round 18
// 93.242 us; speedup vs baseline: 1.7242x; 1.7242x over previous
//
#include <hip/hip_runtime.h>
#include <hip/hip_bf16.h>
#include <math.h>

#define B_ 32
#define T_ 128
#define C_ 64
#define E_ 8
#define HID_ 32

#define LOG2E 1.44269504088896341f

__device__ __forceinline__ float fast_rcp(float x) { return __builtin_amdgcn_rcpf(x); }
__device__ __forceinline__ float fast_exp2(float x) { return exp2f(x); }
__device__ __forceinline__ float fast_sigmoid(float x) {
    return fast_rcp(1.0f + fast_exp2(-LOG2E * x));
}
__device__ __forceinline__ float fast_tanh(float x) {
    float xc = __builtin_amdgcn_fmed3f(x, -15.0f, 15.0f);
    float t = fast_exp2(2.0f * LOG2E * xc);
    return (t - 1.0f) * fast_rcp(t + 1.0f);
}

// DPP lane permute (VALU pipe, ~8 cyc) — all controls used are XOR-symmetric
// (quad_perm) or mirrors, so semantics are direction-unambiguous.
template <int CTRL>
__device__ __forceinline__ float dppf(float v) {
    return __int_as_float(__builtin_amdgcn_update_dpp(
        __float_as_int(v), __float_as_int(v), CTRL, 0xF, 0xF, false));
}
#define QP_XOR1 0xB1   // quad_perm {1,0,3,2}
#define QP_XOR2 0x4E   // quad_perm {2,3,0,1}
#define QP_XOR3 0x1B   // quad_perm {3,2,1,0}
#define HALF_MIRROR 0x141  // lane ^= 7 within each 8-lane half-row

// ---------------------------------------------------------------------------
// K0: xp row + ts_imp for one (b,t). grid = B*T, block = 64. (r17, proven)
// ---------------------------------------------------------------------------
__global__ __launch_bounds__(64) void k_pre_ts(
    const float* __restrict__ x, const float* __restrict__ W_in, const float* __restrict__ b_in,
    const float* __restrict__ W_ts1, const float* __restrict__ b_ts1,
    const float* __restrict__ W_ts2, const float* __restrict__ b_ts2,
    float* __restrict__ xp, float* __restrict__ ts_imp)
{
    const int bt = blockIdx.x;
    const int tid = threadIdx.x;
    __shared__ __align__(16) float xs[C_];
    __shared__ float h1[16];
    if (tid < 16) ((float4*)xs)[tid] = ((const float4*)(x + bt * C_))[tid];
    __syncthreads();

    float a = b_in[tid];
    const float4* w4 = (const float4*)(W_in + tid * C_);
#pragma unroll
    for (int k4 = 0; k4 < 16; ++k4) {
        float4 xv = ((const float4*)xs)[k4];
        float4 wv = w4[k4];
        a = fmaf(xv.x, wv.x, a); a = fmaf(xv.y, wv.y, a);
        a = fmaf(xv.z, wv.z, a); a = fmaf(xv.w, wv.w, a);
    }
    xp[bt * C_ + tid] = a;

    if (tid < 16) {
        float s = b_ts1[tid];
#pragma unroll
        for (int k = 0; k < C_; ++k) s = fmaf(xs[k], W_ts1[tid * C_ + k], s);
        h1[tid] = 0.5f * s * (1.0f + erff(s * 0.70710678118654752f));
    }
    __syncthreads();
    if (tid == 0) {
        float s = b_ts2[0];
#pragma unroll
        for (int k = 0; k < 16; ++k) s = fmaf(h1[k], W_ts2[k], s);
        ts_imp[bt] = fast_sigmoid(s);
    }
}

// ---------------------------------------------------------------------------
// K1: GRU. r14 structure (8 chains/block of 64, 1 unit/lane, 256 blocks)
// but the h all-gather uses DPP xor permutes instead of ds_bpermute:
// pa[m] = h[e ^ m]; weights load-time indexed j = e ^ m.
// ---------------------------------------------------------------------------
__global__ __launch_bounds__(64) void k_gru(
    const float* __restrict__ xp, const float* __restrict__ W_ih, const float* __restrict__ W_hh,
    const float* __restrict__ b_ih, const float* __restrict__ b_hh,
    float* __restrict__ hs, float* __restrict__ fh)
{
    const int tid = threadIdx.x;
    const int ci = tid >> 3;                   // chain-in-block 0..7
    const int e = tid & 7;                     // unit; lane group [8*ci, 8*ci+8)
    const int chain = blockIdx.x * 8 + ci;     // b*C + c
    const int c = chain & 63;

    __shared__ float xc[8][T_ + 1];

    // stage xp columns (8 chains, same b since 8 | 64)
    const int c_base = (blockIdx.x & 7) * 8;
    const int bb = blockIdx.x >> 3;
    for (int idx = tid; idx < 8 * T_; idx += 64) {
        int cci = idx & 7, t = idx >> 3;
        xc[cci][t] = xp[(bb * T_ + t) * C_ + c_base + cci];
    }
    __syncthreads();

    // weights in xor-gather order
    float wr[8], wz[8], wn[8];
#pragma unroll
    for (int m = 0; m < 8; ++m) {
        const int j = e ^ m;
        wr[m] = W_hh[(c * 24 + 0  + e) * 8 + j];
        wz[m] = W_hh[(c * 24 + 8  + e) * 8 + j];
        wn[m] = W_hh[(c * 24 + 16 + e) * 8 + j];
    }
    const float wir = W_ih[c * 24 + e], wiz = W_ih[c * 24 + 8 + e], win = W_ih[c * 24 + 16 + e];
    const float cr = b_ih[c * 24 + e] + b_hh[c * 24 + e];
    const float cz = b_ih[c * 24 + 8 + e] + b_hh[c * 24 + 8 + e];
    const float bin_ = b_ih[c * 24 + 16 + e];
    const float bhn  = b_hh[c * 24 + 16 + e];

    float h = 0.0f;
    float* ho = hs + (size_t)chain * T_ * E_ + e;
    float xv = xc[ci][0];
    for (int t = 0; t < T_; ++t) {
        float xvn = xc[ci][t + 1];             // pad makes t=127 safe
        // all-gather h within the 8-lane group: 4 independent DPP + 3 dependent
        float p1 = dppf<QP_XOR1>(h);           // h[e^1]
        float p2 = dppf<QP_XOR2>(h);           // h[e^2]
        float p3 = dppf<QP_XOR3>(h);           // h[e^3]
        float p7 = dppf<HALF_MIRROR>(h);       // h[e^7]
        float p6 = dppf<HALF_MIRROR>(p1);      // h[e^6]
        float p5 = dppf<HALF_MIRROR>(p2);      // h[e^5]
        float p4 = dppf<HALF_MIRROR>(p3);      // h[e^4]
        const float pa[8] = {h, p1, p2, p3, p4, p5, p6, p7};

        float g0 = fmaf(pa[1], wr[1], pa[0] * wr[0]);
        float g1 = fmaf(pa[3], wr[3], pa[2] * wr[2]);
        float g2 = fmaf(pa[5], wr[5], pa[4] * wr[4]);
        float g3 = fmaf(pa[7], wr[7], pa[6] * wr[6]);
        float gr = fmaf(xv, wir, cr) + ((g0 + g1) + (g2 + g3));
        float z0 = fmaf(pa[1], wz[1], pa[0] * wz[0]);
        float z1 = fmaf(pa[3], wz[3], pa[2] * wz[2]);
        float z2 = fmaf(pa[5], wz[5], pa[4] * wz[4]);
        float z3 = fmaf(pa[7], wz[7], pa[6] * wz[6]);
        float gz = fmaf(xv, wiz, cz) + ((z0 + z1) + (z2 + z3));
        float n0 = fmaf(pa[1], wn[1], pa[0] * wn[0]);
        float n1 = fmaf(pa[3], wn[3], pa[2] * wn[2]);
        float n2 = fmaf(pa[5], wn[5], pa[4] * wn[4]);
        float n3 = fmaf(pa[7], wn[7], pa[6] * wn[6]);
        float hn = bhn + ((n0 + n1) + (n2 + n3));
        float gn = fmaf(xv, win, bin_);
        float r = fast_sigmoid(gr);
        float z = fast_sigmoid(gz);
        float nn = fast_tanh(fmaf(r, hn, gn));
        h = fmaf(z, h - nn, nn);
        ho[t * E_] = h;
        xv = xvn;
    }
    fh[chain * E_ + e] = h;
}

// ---------------------------------------------------------------------------
// K2: attention (r16 proven, 49.6us). grid = B*C, block = 256:
// t2 = tid&63 (rows t2, t2+64), sq = tid>>6 (s in [32sq,32sq+32)).
// ---------------------------------------------------------------------------
__global__ __launch_bounds__(256) void k_attn(
    const float* __restrict__ hs, const float* __restrict__ W_qkv, const float* __restrict__ b_qkv,
    const float* __restrict__ W_o, const float* __restrict__ b_o,
    float* __restrict__ feat_imp, float* __restrict__ tsf_imp)
{
    const int bc = blockIdx.x;
    const int b = bc >> 6, c = bc & 63;
    const int tid = threadIdx.x;
    const int t2 = tid & 63;
    const int sq = tid >> 6;

    __shared__ __align__(16) float ks[T_][E_];
    __shared__ __align__(16) float us[T_][4];
    __shared__ float qsT[E_][T_];
    __shared__ float pacc[3][T_][8];
    __shared__ float red[T_];

    const float qscale = 0.70710678118654752f * LOG2E;

    {
        const int row = (tid < 128) ? tid : (tid - 128);
        const float4* hp = (const float4*)(hs + (size_t)bc * T_ * E_ + row * E_);
        float4 h0 = hp[0], h1 = hp[1];
        float hr[E_] = {h0.x, h0.y, h0.z, h0.w, h1.x, h1.y, h1.z, h1.w};
        if (tid < 128) {
            float kv[E_];
#pragma unroll
            for (int f = 0; f < E_; ++f) {
                float a = b_qkv[E_ + f];
#pragma unroll
                for (int j = 0; j < E_; ++j) a = fmaf(hr[j], W_qkv[(E_ + f) * E_ + j], a);
                kv[f] = a;
            }
            ((float4*)&ks[row][0])[0] = make_float4(kv[0], kv[1], kv[2], kv[3]);
            ((float4*)&ks[row][0])[1] = make_float4(kv[4], kv[5], kv[6], kv[7]);
#pragma unroll
            for (int f = 0; f < E_; ++f) {
                float a = b_qkv[f];
#pragma unroll
                for (int j = 0; j < E_; ++j) a = fmaf(hr[j], W_qkv[f * E_ + j], a);
                qsT[f][row] = a * qscale;
            }
        } else {
            float ws[E_];
#pragma unroll
            for (int d = 0; d < E_; ++d) {
                float wv = 0.0f;
#pragma unroll
                for (int fp = 0; fp < E_; ++fp) wv += W_o[fp * E_ + d];
                ws[d] = wv;
            }
            float vv[E_];
#pragma unroll
            for (int f = 0; f < E_; ++f) {
                float a = b_qkv[2 * E_ + f];
#pragma unroll
                for (int j = 0; j < E_; ++j) a = fmaf(hr[j], W_qkv[(2 * E_ + f) * E_ + j], a);
                vv[f] = a;
            }
            float4 uu;
            uu.x = fmaf(vv[1], ws[1], vv[0] * ws[0]);
            uu.y = fmaf(vv[3], ws[3], vv[2] * ws[2]);
            uu.z = fmaf(vv[5], ws[5], vv[4] * ws[4]);
            uu.w = fmaf(vv[7], ws[7], vv[6] * ws[6]);
            *((float4*)&us[row][0]) = uu;
        }
    }
    __syncthreads();

    float q0[E_], q1[E_];
#pragma unroll
    for (int f = 0; f < E_; ++f) { q0[f] = qsT[f][t2]; q1[f] = qsT[f][t2 + 64]; }

    float l0[4] = {0.f,0.f,0.f,0.f}, S0[4] = {0.f,0.f,0.f,0.f};
    float l1[4] = {0.f,0.f,0.f,0.f}, S1[4] = {0.f,0.f,0.f,0.f};
    const float* kb = &ks[sq * 32][0];
    const float* ub = &us[sq * 32][0];
#pragma unroll 8
    for (int i = 0; i < 32; ++i) {
        float4 k0 = *(const float4*)(kb + i * 8);
        float4 k1 = *(const float4*)(kb + i * 8 + 4);
        float4 uu = *(const float4*)(ub + i * 4);
        float p00 = fast_exp2(fmaf(q0[1], k0.y, q0[0] * k0.x));
        float p01 = fast_exp2(fmaf(q0[3], k0.w, q0[2] * k0.z));
        float p02 = fast_exp2(fmaf(q0[5], k1.y, q0[4] * k1.x));
        float p03 = fast_exp2(fmaf(q0[7], k1.w, q0[6] * k1.z));
        float p10 = fast_exp2(fmaf(q1[1], k0.y, q1[0] * k0.x));
        float p11 = fast_exp2(fmaf(q1[3], k0.w, q1[2] * k0.z));
        float p12 = fast_exp2(fmaf(q1[5], k1.y, q1[4] * k1.x));
        float p13 = fast_exp2(fmaf(q1[7], k1.w, q1[6] * k1.z));
        l0[0] += p00; l0[1] += p01; l0[2] += p02; l0[3] += p03;
        l1[0] += p10; l1[1] += p11; l1[2] += p12; l1[3] += p13;
        S0[0] = fmaf(p00, uu.x, S0[0]); S0[1] = fmaf(p01, uu.y, S0[1]);
        S0[2] = fmaf(p02, uu.z, S0[2]); S0[3] = fmaf(p03, uu.w, S0[3]);
        S1[0] = fmaf(p10, uu.x, S1[0]); S1[1] = fmaf(p11, uu.y, S1[1]);
        S1[2] = fmaf(p12, uu.z, S1[2]); S1[3] = fmaf(p13, uu.w, S1[3]);
    }

    if (sq > 0) {
        float* pr = &pacc[sq - 1][t2][0];
#pragma unroll
        for (int i = 0; i < 4; ++i) { pr[i] = l0[i]; pr[4 + i] = S0[i]; }
        pr = &pacc[sq - 1][t2 + 64][0];
#pragma unroll
        for (int i = 0; i < 4; ++i) { pr[i] = l1[i]; pr[4 + i] = S1[i]; }
    }
    __syncthreads();

    if (sq == 0) {
        float bsum = 0.0f;
#pragma unroll
        for (int fp = 0; fp < E_; ++fp) bsum += b_o[fp];
#pragma unroll
        for (int qq = 0; qq < 3; ++qq) {
#pragma unroll
            for (int i = 0; i < 4; ++i) {
                l0[i] += pacc[qq][t2][i];       S0[i] += pacc[qq][t2][4 + i];
                l1[i] += pacc[qq][t2 + 64][i];  S1[i] += pacc[qq][t2 + 64][4 + i];
            }
        }
        float Sa = bsum, Sb = bsum;
#pragma unroll
        for (int hh = 0; hh < 4; ++hh) {
            Sa = fmaf(S0[hh], fast_rcp(l0[hh]), Sa);
            Sb = fmaf(S1[hh], fast_rcp(l1[hh]), Sb);
        }
        tsf_imp[(size_t)b * T_ * C_ + (size_t)t2 * C_ + c] = fast_sigmoid(Sa);
        tsf_imp[(size_t)b * T_ * C_ + (size_t)(t2 + 64) * C_ + c] = fast_sigmoid(Sb);
        red[t2] = Sa;
        red[t2 + 64] = Sb;
    }
    __syncthreads();
    for (int off = 64; off > 0; off >>= 1) {
        if (tid < off) red[tid] += red[tid + off];
        __syncthreads();
    }
    if (tid == 0) feat_imp[bc] = fast_sigmoid(red[0]);
}

// ---------------------------------------------------------------------------
// K3: out0[b,o] = b_out[o] + sum_k fh[b*C..][k] * W_out[o,k]. grid = B.
// (separate kernel: 32 parallel blocks, not a straggler in a fat kernel)
// ---------------------------------------------------------------------------
__global__ __launch_bounds__(64) void k_out(
    const float* __restrict__ fh, const float* __restrict__ W_out, const float* __restrict__ b_out,
    float* __restrict__ out0)
{
    const int b = blockIdx.x;
    const int tid = threadIdx.x;
    __shared__ float hf[C_ * E_];
    const float4* src = (const float4*)(fh + (b * C_ + tid) * E_);
    float4* dst = (float4*)(hf + tid * E_);
    dst[0] = src[0];
    dst[1] = src[1];
    __syncthreads();
    if (tid < HID_) {
        float a = b_out[tid];
        const float* wo = W_out + tid * (C_ * E_);
        for (int k = 0; k < C_ * E_; ++k) a = fmaf(hf[k], wo[k], a);
        out0[b * HID_ + tid] = a;
    }
}

// ---------------------------------------------------------------------------
extern "C" void kernel_launch(void* const* d_in, const int* in_sizes, int n_in,
                              void* d_out, int out_size, void* d_ws, size_t ws_size,
                              hipStream_t stream) {
    (void)in_sizes; (void)n_in; (void)out_size; (void)ws_size;

    float* out0 = (float*)d_out;                 // (B, HID)    1024
    float* feat = out0 + B_ * HID_;              // (B, C)      2048
    float* tsim = feat + B_ * C_;                // (B, T)      4096
    float* tsf  = tsim + B_ * T_;                // (B, T, C) 262144

    const float* x     = (const float*)d_in[0];
    const float* W_in  = (const float*)d_in[1];
    const float* b_in  = (const float*)d_in[2];
    const float* W_ts1 = (const float*)d_in[3];
    const float* b_ts1 = (const float*)d_in[4];
    const float* W_ts2 = (const float*)d_in[5];
    const float* b_ts2 = (const float*)d_in[6];
    const float* W_ih  = (const float*)d_in[7];
    const float* W_hh  = (const float*)d_in[8];
    const float* b_ih  = (const float*)d_in[9];
    const float* b_hh  = (const float*)d_in[10];
    const float* W_qkv = (const float*)d_in[11];
    const float* b_qkv = (const float*)d_in[12];
    const float* W_o   = (const float*)d_in[13];
    const float* b_o   = (const float*)d_in[14];
    const float* W_out = (const float*)d_in[15];
    const float* b_out = (const float*)d_in[16];

    // ws layout (f32): fh (64KB) | xp (1MB) | hs (8MB)
    float* fhb = (float*)d_ws;
    float* xpb = fhb + B_ * C_ * E_;
    float* hsb = xpb + (size_t)B_ * T_ * C_;

    hipLaunchKernelGGL(k_pre_ts, dim3(B_ * T_), dim3(64), 0, stream,
                       x, W_in, b_in, W_ts1, b_ts1, W_ts2, b_ts2, xpb, tsim);
    hipLaunchKernelGGL(k_gru, dim3(B_ * C_ / 8), dim3(64), 0, stream,
                       xpb, W_ih, W_hh, b_ih, b_hh, hsb, fhb);
    hipLaunchKernelGGL(k_out, dim3(B_), dim3(64), 0, stream,
                       fhb, W_out, b_out, out0);
    hipLaunchKernelGGL(k_attn, dim3(B_ * C_), dim3(256), 0, stream,
                       hsb, W_qkv, b_qkv, W_o, b_o, feat, tsf);
}

// Round 19
// 92.914 us; speedup vs baseline: 1.7303x; 1.0035x over previous
//
#include <hip/hip_runtime.h>
#include <hip/hip_bf16.h>
#include <math.h>

#define B_ 32
#define T_ 128
#define C_ 64
#define E_ 8
#define HID_ 32

#define LOG2E 1.44269504088896341f

__device__ __forceinline__ float fast_rcp(float x) { return __builtin_amdgcn_rcpf(x); }
__device__ __forceinline__ float fast_exp2(float x) { return exp2f(x); }
__device__ __forceinline__ float fast_sigmoid(float x) {
    return fast_rcp(1.0f + fast_exp2(-LOG2E * x));
}
__device__ __forceinline__ float fast_tanh(float x) {
    float xc = __builtin_amdgcn_fmed3f(x, -15.0f, 15.0f);
    float t = fast_exp2(2.0f * LOG2E * xc);
    return (t - 1.0f) * fast_rcp(t + 1.0f);
}

template <int CTRL>
__device__ __forceinline__ float dppf(float v) {
    return __int_as_float(__builtin_amdgcn_update_dpp(
        __float_as_int(v), __float_as_int(v), CTRL, 0xF, 0xF, false));
}
#define QP_XOR1 0xB1
#define QP_XOR2 0x4E
#define QP_XOR3 0x1B
#define HALF_MIRROR 0x141

// ---------------------------------------------------------------------------
// K0: xp row + ts_imp for one (b,t). grid = B*T, block = 64. (proven)
// ---------------------------------------------------------------------------
__global__ __launch_bounds__(64) void k_pre_ts(
    const float* __restrict__ x, const float* __restrict__ W_in, const float* __restrict__ b_in,
    const float* __restrict__ W_ts1, const float* __restrict__ b_ts1,
    const float* __restrict__ W_ts2, const float* __restrict__ b_ts2,
    float* __restrict__ xp, float* __restrict__ ts_imp)
{
    const int bt = blockIdx.x;
    const int tid = threadIdx.x;
    __shared__ __align__(16) float xs[C_];
    __shared__ float h1[16];
    if (tid < 16) ((float4*)xs)[tid] = ((const float4*)(x + bt * C_))[tid];
    __syncthreads();

    float a = b_in[tid];
    const float4* w4 = (const float4*)(W_in + tid * C_);
#pragma unroll
    for (int k4 = 0; k4 < 16; ++k4) {
        float4 xv = ((const float4*)xs)[k4];
        float4 wv = w4[k4];
        a = fmaf(xv.x, wv.x, a); a = fmaf(xv.y, wv.y, a);
        a = fmaf(xv.z, wv.z, a); a = fmaf(xv.w, wv.w, a);
    }
    xp[bt * C_ + tid] = a;

    if (tid < 16) {
        float s = b_ts1[tid];
#pragma unroll
        for (int k = 0; k < C_; ++k) s = fmaf(xs[k], W_ts1[tid * C_ + k], s);
        h1[tid] = 0.5f * s * (1.0f + erff(s * 0.70710678118654752f));
    }
    __syncthreads();
    if (tid == 0) {
        float s = b_ts2[0];
#pragma unroll
        for (int k = 0; k < 16; ++k) s = fmaf(h1[k], W_ts2[k], s);
        ts_imp[bt] = fast_sigmoid(s);
    }
}

// ---------------------------------------------------------------------------
// K1: GRU (r18, unchanged — at its latency floor pending deeper probe).
// ---------------------------------------------------------------------------
__global__ __launch_bounds__(64) void k_gru(
    const float* __restrict__ xp, const float* __restrict__ W_ih, const float* __restrict__ W_hh,
    const float* __restrict__ b_ih, const float* __restrict__ b_hh,
    float* __restrict__ hs, float* __restrict__ fh)
{
    const int tid = threadIdx.x;
    const int ci = tid >> 3;
    const int e = tid & 7;
    const int chain = blockIdx.x * 8 + ci;
    const int c = chain & 63;

    __shared__ float xc[8][T_ + 1];

    const int c_base = (blockIdx.x & 7) * 8;
    const int bb = blockIdx.x >> 3;
    for (int idx = tid; idx < 8 * T_; idx += 64) {
        int cci = idx & 7, t = idx >> 3;
        xc[cci][t] = xp[(bb * T_ + t) * C_ + c_base + cci];
    }
    __syncthreads();

    float wr[8], wz[8], wn[8];
#pragma unroll
    for (int m = 0; m < 8; ++m) {
        const int j = e ^ m;
        wr[m] = W_hh[(c * 24 + 0  + e) * 8 + j];
        wz[m] = W_hh[(c * 24 + 8  + e) * 8 + j];
        wn[m] = W_hh[(c * 24 + 16 + e) * 8 + j];
    }
    const float wir = W_ih[c * 24 + e], wiz = W_ih[c * 24 + 8 + e], win = W_ih[c * 24 + 16 + e];
    const float cr = b_ih[c * 24 + e] + b_hh[c * 24 + e];
    const float cz = b_ih[c * 24 + 8 + e] + b_hh[c * 24 + 8 + e];
    const float bin_ = b_ih[c * 24 + 16 + e];
    const float bhn  = b_hh[c * 24 + 16 + e];

    float h = 0.0f;
    float* ho = hs + (size_t)chain * T_ * E_ + e;
    float xv = xc[ci][0];
    for (int t = 0; t < T_; ++t) {
        float xvn = xc[ci][t + 1];
        float p1 = dppf<QP_XOR1>(h);
        float p2 = dppf<QP_XOR2>(h);
        float p3 = dppf<QP_XOR3>(h);
        float p7 = dppf<HALF_MIRROR>(h);
        float p6 = dppf<HALF_MIRROR>(p1);
        float p5 = dppf<HALF_MIRROR>(p2);
        float p4 = dppf<HALF_MIRROR>(p3);
        const float pa[8] = {h, p1, p2, p3, p4, p5, p6, p7};

        float g0 = fmaf(pa[1], wr[1], pa[0] * wr[0]);
        float g1 = fmaf(pa[3], wr[3], pa[2] * wr[2]);
        float g2 = fmaf(pa[5], wr[5], pa[4] * wr[4]);
        float g3 = fmaf(pa[7], wr[7], pa[6] * wr[6]);
        float gr = fmaf(xv, wir, cr) + ((g0 + g1) + (g2 + g3));
        float z0 = fmaf(pa[1], wz[1], pa[0] * wz[0]);
        float z1 = fmaf(pa[3], wz[3], pa[2] * wz[2]);
        float z2 = fmaf(pa[5], wz[5], pa[4] * wz[4]);
        float z3 = fmaf(pa[7], wz[7], pa[6] * wz[6]);
        float gz = fmaf(xv, wiz, cz) + ((z0 + z1) + (z2 + z3));
        float n0 = fmaf(pa[1], wn[1], pa[0] * wn[0]);
        float n1 = fmaf(pa[3], wn[3], pa[2] * wn[2]);
        float n2 = fmaf(pa[5], wn[5], pa[4] * wn[4]);
        float n3 = fmaf(pa[7], wn[7], pa[6] * wn[6]);
        float hn = bhn + ((n0 + n1) + (n2 + n3));
        float gn = fmaf(xv, win, bin_);
        float r = fast_sigmoid(gr);
        float z = fast_sigmoid(gz);
        float nn = fast_tanh(fmaf(r, hn, gn));
        h = fmaf(z, h - nn, nn);
        ho[t * E_] = h;
        xv = xvn;
    }
    fh[chain * E_ + e] = h;
}

// ---------------------------------------------------------------------------
// K2: attention, low-LDS layout. grid = B*C, block = 256 = 4 waves.
// Wave w owns rows [32w, 32w+32); lane = 2*ri+sh: row = 32w+ri,
// s in [64*sh, 64*sh+64). Partner combine via shfl_xor(1); no pacc,
// 1 block barrier total. LDS ~10.3 KB -> high residency.
// ---------------------------------------------------------------------------
__global__ __launch_bounds__(256) void k_attn(
    const float* __restrict__ hs, const float* __restrict__ W_qkv, const float* __restrict__ b_qkv,
    const float* __restrict__ W_o, const float* __restrict__ b_o,
    float* __restrict__ feat_imp, float* __restrict__ tsf_imp)
{
    const int bc = blockIdx.x;
    const int b = bc >> 6, c = bc & 63;
    const int tid = threadIdx.x;
    const int w = tid >> 6;
    const int lane = tid & 63;
    const int ri = lane >> 1;
    const int sh = lane & 1;
    const int row = w * 32 + ri;

    __shared__ __align__(16) float ks[T_][E_];   // 4 KB
    __shared__ __align__(16) float us[T_][4];    // 2 KB
    __shared__ float qsT[E_][T_];                // 4 KB
    __shared__ float red4[4];

    const float qscale = 0.70710678118654752f * LOG2E;

    // staging: tid<128 -> q+k of row tid; tid>=128 -> u of row tid-128
    {
        const int srow = (tid < 128) ? tid : (tid - 128);
        const float4* hp = (const float4*)(hs + (size_t)bc * T_ * E_ + srow * E_);
        float4 h0 = hp[0], h1 = hp[1];
        float hr[E_] = {h0.x, h0.y, h0.z, h0.w, h1.x, h1.y, h1.z, h1.w};
        if (tid < 128) {
            float kv[E_];
#pragma unroll
            for (int f = 0; f < E_; ++f) {
                float a = b_qkv[E_ + f];
#pragma unroll
                for (int j = 0; j < E_; ++j) a = fmaf(hr[j], W_qkv[(E_ + f) * E_ + j], a);
                kv[f] = a;
            }
            ((float4*)&ks[srow][0])[0] = make_float4(kv[0], kv[1], kv[2], kv[3]);
            ((float4*)&ks[srow][0])[1] = make_float4(kv[4], kv[5], kv[6], kv[7]);
#pragma unroll
            for (int f = 0; f < E_; ++f) {
                float a = b_qkv[f];
#pragma unroll
                for (int j = 0; j < E_; ++j) a = fmaf(hr[j], W_qkv[f * E_ + j], a);
                qsT[f][srow] = a * qscale;
            }
        } else {
            float ws[E_];
#pragma unroll
            for (int d = 0; d < E_; ++d) {
                float wv = 0.0f;
#pragma unroll
                for (int fp = 0; fp < E_; ++fp) wv += W_o[fp * E_ + d];
                ws[d] = wv;
            }
            float vv[E_];
#pragma unroll
            for (int f = 0; f < E_; ++f) {
                float a = b_qkv[2 * E_ + f];
#pragma unroll
                for (int j = 0; j < E_; ++j) a = fmaf(hr[j], W_qkv[(2 * E_ + f) * E_ + j], a);
                vv[f] = a;
            }
            float4 uu;
            uu.x = fmaf(vv[1], ws[1], vv[0] * ws[0]);
            uu.y = fmaf(vv[3], ws[3], vv[2] * ws[2]);
            uu.z = fmaf(vv[5], ws[5], vv[4] * ws[4]);
            uu.w = fmaf(vv[7], ws[7], vv[6] * ws[6]);
            *((float4*)&us[srow][0]) = uu;
        }
    }
    __syncthreads();

    // q for this lane's row: qsT[f][row], pairs broadcast -> conflict-free
    float q[E_];
#pragma unroll
    for (int f = 0; f < E_; ++f) q[f] = qsT[f][row];

    // main loop: this lane's 64 s-values (2 distinct LDS addrs per wave = free)
    float l[4] = {0.f, 0.f, 0.f, 0.f};
    float S[4] = {0.f, 0.f, 0.f, 0.f};
    const float* kb = &ks[sh * 64][0];
    const float* ub = &us[sh * 64][0];
#pragma unroll 8
    for (int i = 0; i < 64; ++i) {
        float4 k0 = *(const float4*)(kb + i * 8);
        float4 k1 = *(const float4*)(kb + i * 8 + 4);
        float4 uu = *(const float4*)(ub + i * 4);
        float p0 = fast_exp2(fmaf(q[1], k0.y, q[0] * k0.x));
        float p1 = fast_exp2(fmaf(q[3], k0.w, q[2] * k0.z));
        float p2 = fast_exp2(fmaf(q[5], k1.y, q[4] * k1.x));
        float p3 = fast_exp2(fmaf(q[7], k1.w, q[6] * k1.z));
        l[0] += p0; l[1] += p1; l[2] += p2; l[3] += p3;
        S[0] = fmaf(p0, uu.x, S[0]);
        S[1] = fmaf(p1, uu.y, S[1]);
        S[2] = fmaf(p2, uu.z, S[2]);
        S[3] = fmaf(p3, uu.w, S[3]);
    }

    // combine the two s-halves (partner lane), both lanes get full sums
#pragma unroll
    for (int i = 0; i < 4; ++i) {
        l[i] += __shfl_xor(l[i], 1);
        S[i] += __shfl_xor(S[i], 1);
    }

    float bsum = 0.0f;
#pragma unroll
    for (int fp = 0; fp < E_; ++fp) bsum += b_o[fp];
    float Sv = bsum;
#pragma unroll
    for (int hh = 0; hh < 4; ++hh) Sv = fmaf(S[hh], fast_rcp(l[hh]), Sv);

    if (sh == 0)
        tsf_imp[(size_t)b * T_ * C_ + (size_t)row * C_ + c] = fast_sigmoid(Sv);

    // feat: parity-safe butterfly (offsets 2..32) sums the wave's 32 rows
    float fsum = Sv;
#pragma unroll
    for (int off = 2; off <= 32; off <<= 1) fsum += __shfl_xor(fsum, off);
    if (lane == 0) red4[w] = fsum;
    __syncthreads();
    if (tid == 0)
        feat_imp[bc] = fast_sigmoid(red4[0] + red4[1] + red4[2] + red4[3]);
}

// ---------------------------------------------------------------------------
// K3: out0. grid = B, block = 64. (proven, ~2us)
// ---------------------------------------------------------------------------
__global__ __launch_bounds__(64) void k_out(
    const float* __restrict__ fh, const float* __restrict__ W_out, const float* __restrict__ b_out,
    float* __restrict__ out0)
{
    const int b = blockIdx.x;
    const int tid = threadIdx.x;
    __shared__ float hf[C_ * E_];
    const float4* src = (const float4*)(fh + (b * C_ + tid) * E_);
    float4* dst = (float4*)(hf + tid * E_);
    dst[0] = src[0];
    dst[1] = src[1];
    __syncthreads();
    if (tid < HID_) {
        float a = b_out[tid];
        const float* wo = W_out + tid * (C_ * E_);
        for (int k = 0; k < C_ * E_; ++k) a = fmaf(hf[k], wo[k], a);
        out0[b * HID_ + tid] = a;
    }
}

// ---------------------------------------------------------------------------
extern "C" void kernel_launch(void* const* d_in, const int* in_sizes, int n_in,
                              void* d_out, int out_size, void* d_ws, size_t ws_size,
                              hipStream_t stream) {
    (void)in_sizes; (void)n_in; (void)out_size; (void)ws_size;

    float* out0 = (float*)d_out;                 // (B, HID)    1024
    float* feat = out0 + B_ * HID_;              // (B, C)      2048
    float* tsim = feat + B_ * C_;                // (B, T)      4096
    float* tsf  = tsim + B_ * T_;                // (B, T, C) 262144

    const float* x     = (const float*)d_in[0];
    const float* W_in  = (const float*)d_in[1];
    const float* b_in  = (const float*)d_in[2];
    const float* W_ts1 = (const float*)d_in[3];
    const float* b_ts1 = (const float*)d_in[4];
    const float* W_ts2 = (const float*)d_in[5];
    const float* b_ts2 = (const float*)d_in[6];
    const float* W_ih  = (const float*)d_in[7];
    const float* W_hh  = (const float*)d_in[8];
    const float* b_ih  = (const float*)d_in[9];
    const float* b_hh  = (const float*)d_in[10];
    const float* W_qkv = (const float*)d_in[11];
    const float* b_qkv = (const float*)d_in[12];
    const float* W_o   = (const float*)d_in[13];
    const float* b_o   = (const float*)d_in[14];
    const float* W_out = (const float*)d_in[15];
    const float* b_out = (const float*)d_in[16];

    // ws layout (f32): fh (64KB) | xp (1MB) | hs (8MB)
    float* fhb = (float*)d_ws;
    float* xpb = fhb + B_ * C_ * E_;
    float* hsb = xpb + (size_t)B_ * T_ * C_;

    hipLaunchKernelGGL(k_pre_ts, dim3(B_ * T_), dim3(64), 0, stream,
                       x, W_in, b_in, W_ts1, b_ts1, W_ts2, b_ts2, xpb, tsim);
    hipLaunchKernelGGL(k_gru, dim3(B_ * C_ / 8), dim3(64), 0, stream,
                       xpb, W_ih, W_hh, b_ih, b_hh, hsb, fhb);
    hipLaunchKernelGGL(k_out, dim3(B_), dim3(64), 0, stream,
                       fhb, W_out, b_out, out0);
    hipLaunchKernelGGL(k_attn, dim3(B_ * C_), dim3(256), 0, stream,
                       hsb, W_qkv, b_qkv, W_o, b_o, feat, tsf);
}